// Round 5
// baseline (263.432 us; speedup 1.0000x reference)
//
#include <hip/hip_runtime.h>
#include <math.h>

// Fully fused CNN + head, one block (256 threads) per image, single launch.
// LDS: arena[4620]  conv1-out halo [4][33][35] -> conv2-out halo [8][18][18] -> head scratch
//      w3s[1168] = w3 + b3;  csang[113] = cos/sin angles + z.   Peak ~23.6 KB -> 6 blocks/CU.
__global__ __launch_bounds__(256, 6)
void fused_all(const float* __restrict__ x,
               const float* __restrict__ w1, const float* __restrict__ b1,
               const float* __restrict__ w2, const float* __restrict__ b2,
               const float* __restrict__ w3, const float* __restrict__ b3,
               const float* __restrict__ wf, const float* __restrict__ bf,
               const float* __restrict__ qw,
               const float* __restrict__ wc1, const float* __restrict__ bc1,
               const float* __restrict__ wc2, const float* __restrict__ bc2,
               const float* __restrict__ wc3, const float* __restrict__ bc3,
               const float* __restrict__ wc4, const float* __restrict__ bc4,
               const float* __restrict__ wc5, const float* __restrict__ bc5,
               float* __restrict__ out)
{
    __shared__ __align__(16) float arena[4620];
    __shared__ __align__(16) float w3s[1168];
    __shared__ __align__(16) float csang[113];   // [0,56) cos, [56,112) sin, [112] z

    // head scratch overlay (valid after conv3 completes); offsets keep 16B alignment
    float* pool  = arena;         // 64
    float* feats = arena + 64;    // 256
    float* h1    = arena + 320;   // 200
    float* h2    = arena + 520;   // 150
    float* h3    = arena + 672;   // 100  (16B aligned)
    float* h4    = arena + 772;   // 50   (16B aligned)

    const int tid  = threadIdx.x;
    const int b    = blockIdx.x;
    const int lane = tid & 63;

    // ---- stage w3/b3, angles; zero conv1-out halo ----
    for (int i = tid; i < 1168; i += 256) w3s[i] = (i < 1152) ? w3[i] : b3[i - 1152];
    if (tid < 56) {
        float th = qw[tid] * 0.5f;
        csang[tid]      = cosf(th);
        csang[56 + tid] = sinf(th);
    }
    for (int i = tid; i < 140; i += 256) { int oc = i / 35, c = i - oc * 35; arena[oc * 1155 + c] = 0.f; }
    for (int i = tid; i < 132; i += 256) { int oc = i / 33, r = i - oc * 33; arena[oc * 1155 + r * 35] = 0.f; }

    // ---- conv1: x from GLOBAL, k5 s2 p2, 4 oc x 4 px per thread ----
    {
        const float* xb = x + (size_t)b * 4096;
        const int oh  = tid >> 3;
        const int ow  = tid & 7;
        const int ow0 = ow * 4;
        const int c0  = ow0 * 2 - 2;
        const bool cmL = (ow == 0);
        const bool cmR = (ow == 7);
        float acc[4][4];
        #pragma unroll
        for (int oc = 0; oc < 4; oc++) {
            const float bv = b1[oc];
            #pragma unroll
            for (int j = 0; j < 4; j++) acc[oc][j] = bv;
        }
        #pragma unroll
        for (int kh = 0; kh < 5; kh++) {
            const int ih = oh * 2 - 2 + kh;
            if (ih >= 0 && ih < 64) {
                const float* row = xb + ih * 64;
                float colv[11];
                {
                    float v0 = row[cmL ? 0 : c0];
                    float v1 = row[cmL ? 0 : c0 + 1];
                    float vA = row[cmR ? 63 : c0 + 10];
                    colv[0]  = cmL ? 0.f : v0;
                    colv[1]  = cmL ? 0.f : v1;
                    colv[10] = cmR ? 0.f : vA;
                }
                #pragma unroll
                for (int cc = 2; cc < 10; cc++) colv[cc] = row[c0 + cc];
                #pragma unroll
                for (int kw = 0; kw < 5; kw++) {
                    #pragma unroll
                    for (int oc = 0; oc < 4; oc++) {
                        const float wv = w1[oc * 25 + kh * 5 + kw];
                        acc[oc][0] = fmaf(colv[0 + kw], wv, acc[oc][0]);
                        acc[oc][1] = fmaf(colv[2 + kw], wv, acc[oc][1]);
                        acc[oc][2] = fmaf(colv[4 + kw], wv, acc[oc][2]);
                        acc[oc][3] = fmaf(colv[6 + kw], wv, acc[oc][3]);
                    }
                }
            }
        }
        #pragma unroll
        for (int oc = 0; oc < 4; oc++) {
            float* o = arena + oc * 1155 + (oh + 1) * 35 + ow0 + 1;
            #pragma unroll
            for (int j = 0; j < 4; j++) o[j] = fmaxf(acc[oc][j], 0.f);
        }
    }
    __syncthreads();

    // ---- conv2: arena [4][33][35] -> registers, k3 s2 p1, 2 oc x 4 px per thread ----
    float r2[2][4];
    {
        const int oc0 = __builtin_amdgcn_readfirstlane(tid >> 6);
        const int oh  = lane >> 2, ow0 = (lane & 3) * 4;
        {
            const float ba = b2[oc0], bb = b2[oc0 + 4];
            #pragma unroll
            for (int j = 0; j < 4; j++) { r2[0][j] = ba; r2[1][j] = bb; }
        }
        const int c0s = ow0 * 2;
        #pragma unroll
        for (int ic = 0; ic < 4; ic++) {
            const float* base = arena + ic * 1155;
            #pragma unroll
            for (int kh = 0; kh < 3; kh++) {
                const int ihs = oh * 2 + kh;
                float colv[9];
                #pragma unroll
                for (int cc = 0; cc < 9; cc++) colv[cc] = base[ihs * 35 + c0s + cc];
                #pragma unroll
                for (int kw = 0; kw < 3; kw++) {
                    const float wa = w2[((oc0    ) * 4 + ic) * 9 + kh * 3 + kw];
                    const float wb = w2[((oc0 + 4) * 4 + ic) * 9 + kh * 3 + kw];
                    #pragma unroll
                    for (int j = 0; j < 4; j++) {
                        r2[0][j] = fmaf(colv[2 * j + kw], wa, r2[0][j]);
                        r2[1][j] = fmaf(colv[2 * j + kw], wb, r2[1][j]);
                    }
                }
            }
        }
    }
    __syncthreads();

    // ---- conv2-out halo [8][18][18] overlay ----
    for (int i = tid; i < 576; i += 256) {
        const int ch = i / 72, j = i - ch * 72;
        if (j < 18)      arena[ch * 324 + j] = 0.f;
        else if (j < 36) arena[ch * 324 + 17 * 18 + (j - 18)] = 0.f;
        else if (j < 52) arena[ch * 324 + (j - 35) * 18] = 0.f;
        else if (j < 68) arena[ch * 324 + (j - 51) * 18 + 17] = 0.f;
    }
    {
        const int oc0 = __builtin_amdgcn_readfirstlane(tid >> 6);
        const int oh  = lane >> 2, ow0 = (lane & 3) * 4;
        float* oA = arena + oc0 * 324       + (oh + 1) * 18 + ow0 + 1;
        float* oB = arena + (oc0 + 4) * 324 + (oh + 1) * 18 + ow0 + 1;
        #pragma unroll
        for (int j = 0; j < 4; j++) { oA[j] = fmaxf(r2[0][j], 0.f); oB[j] = fmaxf(r2[1][j], 0.f); }
    }
    __syncthreads();

    // ---- conv3 + fused 8x8 avg pool: thread = (oc, 4x4 tile) ----
    float ps;
    int psw;   // whether this lane writes, and where
    {
        const int oc = tid >> 4, s = tid & 15;
        const int tr = (s >> 2) * 4, tc = (s & 3) * 4;
        float acc[16];
        const float bv = w3s[1152 + oc];
        #pragma unroll
        for (int k = 0; k < 16; k++) acc[k] = bv;
        #pragma unroll
        for (int ic = 0; ic < 8; ic++) {
            const float* xc = arena + ic * 324;
            float p[6][6];
            #pragma unroll
            for (int dr = 0; dr < 6; dr++)
                #pragma unroll
                for (int dc = 0; dc < 6; dc++)
                    p[dr][dc] = xc[(tr + dr) * 18 + (tc + dc)];
            float wv[9];
            #pragma unroll
            for (int k = 0; k < 9; k++) wv[k] = w3s[oc * 72 + ic * 9 + k];
            #pragma unroll
            for (int r = 0; r < 4; r++)
                #pragma unroll
                for (int c = 0; c < 4; c++) {
                    float a = acc[r * 4 + c];
                    #pragma unroll
                    for (int kh = 0; kh < 3; kh++)
                        #pragma unroll
                        for (int kw = 0; kw < 3; kw++)
                            a = fmaf(p[r + kh][c + kw], wv[kh * 3 + kw], a);
                    acc[r * 4 + c] = a;
                }
        }
        ps = 0.f;
        #pragma unroll
        for (int k = 0; k < 16; k++) ps += fmaxf(acc[k], 0.f);
        ps += __shfl_xor(ps, 1, 64);
        ps += __shfl_xor(ps, 4, 64);
        const int ii = s >> 3, jj = (s >> 1) & 1;
        psw = ((s & 5) == 0) ? (oc * 4 + ii * 2 + jj) : -1;
    }
    __syncthreads();                       // conv2-out reads done; arena free for head
    if (psw >= 0) pool[psw] = ps * (1.f / 64.f);
    __syncthreads();

    // ---- fc: feats[tid] = relu(dot64(pool, wf row) + bf) ----
    {
        float acc = bf[tid];
        const float4* wr = (const float4*)(wf + tid * 64);
        const float4* pl = (const float4*)pool;
        #pragma unroll
        for (int kc = 0; kc < 4; kc++) {
            float4 w0 = wr[kc * 4 + 0], w1_ = wr[kc * 4 + 1], w2_ = wr[kc * 4 + 2], w3_ = wr[kc * 4 + 3];
            float4 p0 = pl[kc * 4 + 0], p1 = pl[kc * 4 + 1], p2 = pl[kc * 4 + 2], p3 = pl[kc * 4 + 3];
            acc = fmaf(w0.x, p0.x, acc); acc = fmaf(w0.y, p0.y, acc); acc = fmaf(w0.z, p0.z, acc); acc = fmaf(w0.w, p0.w, acc);
            acc = fmaf(w1_.x, p1.x, acc); acc = fmaf(w1_.y, p1.y, acc); acc = fmaf(w1_.z, p1.z, acc); acc = fmaf(w1_.w, p1.w, acc);
            acc = fmaf(w2_.x, p2.x, acc); acc = fmaf(w2_.y, p2.y, acc); acc = fmaf(w2_.z, p2.z, acc); acc = fmaf(w2_.w, p2.w, acc);
            acc = fmaf(w3_.x, p3.x, acc); acc = fmaf(w3_.y, p3.y, acc); acc = fmaf(w3_.z, p3.z, acc); acc = fmaf(w3_.w, p3.w, acc);
        }
        feats[tid] = fmaxf(acc, 0.f);
    }
    __syncthreads();

    // ---- quantum circuit: wave 0 only; amp idx = j*64 + lane ----
    if (tid < 64) {
        float v0 = feats[lane], v1 = feats[64 + lane];
        float v2 = feats[128 + lane], v3 = feats[192 + lane];
        float ssq = v0 * v0 + v1 * v1 + v2 * v2 + v3 * v3;
        #pragma unroll
        for (int off = 1; off < 64; off <<= 1) ssq += __shfl_xor(ssq, off, 64);
        const float inv = 1.0f / fmaxf(sqrtf(ssq), 1e-12f);
        v0 *= inv; v1 *= inv; v2 *= inv; v3 *= inv;

        for (int l = 0; l < 7; l++) {
            {   // RY q=0 (j bit1) then q=1 (j bit0)
                float c = csang[l * 8 + 0], s = csang[56 + l * 8 + 0];
                float n0 = c * v0 - s * v2, n2 = s * v0 + c * v2;
                float n1 = c * v1 - s * v3, n3 = s * v1 + c * v3;
                float c1 = csang[l * 8 + 1], s1 = csang[56 + l * 8 + 1];
                v0 = c1 * n0 - s1 * n1; v1 = s1 * n0 + c1 * n1;
                v2 = c1 * n2 - s1 * n3; v3 = s1 * n2 + c1 * n3;
            }
            #pragma unroll
            for (int q = 2; q < 8; q++) {
                const int m = 1 << (7 - q);
                const float c = csang[l * 8 + q], s = csang[56 + l * 8 + q];
                const float sgn = (lane & m) ? s : -s;
                float t0 = __shfl_xor(v0, m, 64);
                float t1 = __shfl_xor(v1, m, 64);
                float t2 = __shfl_xor(v2, m, 64);
                float t3 = __shfl_xor(v3, m, 64);
                v0 = fmaf(sgn, t0, c * v0);
                v1 = fmaf(sgn, t1, c * v1);
                v2 = fmaf(sgn, t2, c * v2);
                v3 = fmaf(sgn, t3, c * v3);
            }
            { float t = v2; v2 = v3; v3 = t; }
            v1 = __shfl_xor(v1, 32, 64);
            v3 = __shfl_xor(v3, 32, 64);
            #pragma unroll
            for (int q = 2; q < 7; q++) {
                const int mc = 1 << (7 - q), mt = 1 << (6 - q);
                float t0 = __shfl_xor(v0, mt, 64);
                float t1 = __shfl_xor(v1, mt, 64);
                float t2 = __shfl_xor(v2, mt, 64);
                float t3 = __shfl_xor(v3, mt, 64);
                if (lane & mc) { v0 = t0; v1 = t1; v2 = t2; v3 = t3; }
            }
        }
        float m0 = v0 * v0 + v1 * v1 - v2 * v2 - v3 * v3;
        #pragma unroll
        for (int off = 1; off < 64; off <<= 1) m0 += __shfl_xor(m0, off, 64);
        if (lane == 0) csang[112] = m0;
    }
    __syncthreads();

    // ---- classifier MLP ----
    const float z = csang[112];
    if (tid < 200) h1[tid] = fmaxf(fmaf(z, wc1[tid], bc1[tid]), 0.f);
    __syncthreads();
    if (tid < 150) {
        float acc = bc2[tid];
        const float4* wr = (const float4*)(wc2 + tid * 200);
        const float4* hp = (const float4*)h1;
        #pragma unroll 5
        for (int kc = 0; kc < 25; kc++) {
            float4 wa = wr[2 * kc], wb = wr[2 * kc + 1];
            float4 ha = hp[2 * kc], hb = hp[2 * kc + 1];
            acc = fmaf(wa.x, ha.x, acc); acc = fmaf(wa.y, ha.y, acc); acc = fmaf(wa.z, ha.z, acc); acc = fmaf(wa.w, ha.w, acc);
            acc = fmaf(wb.x, hb.x, acc); acc = fmaf(wb.y, hb.y, acc); acc = fmaf(wb.z, hb.z, acc); acc = fmaf(wb.w, hb.w, acc);
        }
        h2[tid] = fmaxf(acc, 0.f);
    }
    __syncthreads();
    if (tid < 100) {
        float acc = bc3[tid];
        const float2* wr = (const float2*)(wc3 + tid * 150);
        const float2* hp = (const float2*)h2;
        #pragma unroll 15
        for (int k = 0; k < 75; k++) {
            float2 wa = wr[k], hv = hp[k];
            acc = fmaf(wa.x, hv.x, fmaf(wa.y, hv.y, acc));
        }
        h3[tid] = fmaxf(acc, 0.f);
    }
    __syncthreads();
    if (tid < 50) {
        float acc = bc4[tid];
        const float4* wr = (const float4*)(wc4 + tid * 100);
        const float4* hp = (const float4*)h3;
        #pragma unroll
        for (int kc = 0; kc < 25; kc++) {
            float4 wa = wr[kc], hv = hp[kc];
            acc = fmaf(wa.x, hv.x, acc); acc = fmaf(wa.y, hv.y, acc);
            acc = fmaf(wa.z, hv.z, acc); acc = fmaf(wa.w, hv.w, acc);
        }
        h4[tid] = fmaxf(acc, 0.f);
    }
    __syncthreads();
    if (tid == 0) {
        float acc = bc5[0];
        const float2* wr = (const float2*)wc5;
        const float2* hp = (const float2*)h4;
        #pragma unroll
        for (int k = 0; k < 25; k++) {
            float2 wa = wr[k], hv = hp[k];
            acc = fmaf(wa.x, hv.x, fmaf(wa.y, hv.y, acc));
        }
        out[b] = 1.0f / (1.0f + expf(-acc));
    }
}

extern "C" void kernel_launch(void* const* d_in, const int* in_sizes, int n_in,
                              void* d_out, int out_size, void* d_ws, size_t ws_size,
                              hipStream_t stream) {
    const float* x   = (const float*)d_in[0];
    const float* w1  = (const float*)d_in[1];
    const float* b1  = (const float*)d_in[2];
    const float* w2  = (const float*)d_in[3];
    const float* b2  = (const float*)d_in[4];
    const float* w3  = (const float*)d_in[5];
    const float* b3  = (const float*)d_in[6];
    const float* wf  = (const float*)d_in[7];
    const float* bf  = (const float*)d_in[8];
    const float* qw  = (const float*)d_in[9];
    const float* wc1 = (const float*)d_in[10];
    const float* bc1 = (const float*)d_in[11];
    const float* wc2 = (const float*)d_in[12];
    const float* bc2 = (const float*)d_in[13];
    const float* wc3 = (const float*)d_in[14];
    const float* bc3 = (const float*)d_in[15];
    const float* wc4 = (const float*)d_in[16];
    const float* bc4 = (const float*)d_in[17];
    const float* wc5 = (const float*)d_in[18];
    const float* bc5 = (const float*)d_in[19];
    float* out = (float*)d_out;

    fused_all<<<4096, 256, 0, stream>>>(x, w1, b1, w2, b2, w3, b3, wf, bf, qw,
                                        wc1, bc1, wc2, bc2, wc3, bc3,
                                        wc4, bc4, wc5, bc5, out);
}

// Round 6
// 227.260 us; speedup vs baseline: 1.1592x; 1.1592x over previous
//
#include <hip/hip_runtime.h>
#include <math.h>

// ================= Kernel A: conv1+conv2+conv3+pool fused, one block per image =================
// (unchanged from round 4: measured 71 us, VALU-issue ~82%, near packed-FMA floor)
__global__ __launch_bounds__(256, 6)
void convpool_kernel(const float* __restrict__ x,
                     const float* __restrict__ w1, const float* __restrict__ b1,
                     const float* __restrict__ w2, const float* __restrict__ b2,
                     const float* __restrict__ w3, const float* __restrict__ b3,
                     float* __restrict__ poolout)
{
    __shared__ __align__(16) float arena[4620];
    __shared__ __align__(16) float w3s[1168];
    const int tid  = threadIdx.x;
    const int b    = blockIdx.x;
    const int lane = tid & 63;

    for (int i = tid; i < 1168; i += 256) w3s[i] = (i < 1152) ? w3[i] : b3[i - 1152];
    for (int i = tid; i < 140; i += 256) { int oc = i / 35, c = i - oc * 35; arena[oc * 1155 + c] = 0.f; }
    for (int i = tid; i < 132; i += 256) { int oc = i / 33, r = i - oc * 33; arena[oc * 1155 + r * 35] = 0.f; }

    // ---- conv1 ----
    {
        const float* xb = x + (size_t)b * 4096;
        const int oh  = tid >> 3;
        const int ow  = tid & 7;
        const int ow0 = ow * 4;
        const int c0  = ow0 * 2 - 2;
        const bool cmL = (ow == 0);
        const bool cmR = (ow == 7);
        float acc[4][4];
        #pragma unroll
        for (int oc = 0; oc < 4; oc++) {
            const float bv = b1[oc];
            #pragma unroll
            for (int j = 0; j < 4; j++) acc[oc][j] = bv;
        }
        #pragma unroll
        for (int kh = 0; kh < 5; kh++) {
            const int ih = oh * 2 - 2 + kh;
            if (ih >= 0 && ih < 64) {
                const float* row = xb + ih * 64;
                float colv[11];
                {
                    float v0 = row[cmL ? 0 : c0];
                    float v1 = row[cmL ? 0 : c0 + 1];
                    float vA = row[cmR ? 63 : c0 + 10];
                    colv[0]  = cmL ? 0.f : v0;
                    colv[1]  = cmL ? 0.f : v1;
                    colv[10] = cmR ? 0.f : vA;
                }
                #pragma unroll
                for (int cc = 2; cc < 10; cc++) colv[cc] = row[c0 + cc];
                #pragma unroll
                for (int kw = 0; kw < 5; kw++) {
                    #pragma unroll
                    for (int oc = 0; oc < 4; oc++) {
                        const float wv = w1[oc * 25 + kh * 5 + kw];
                        acc[oc][0] = fmaf(colv[0 + kw], wv, acc[oc][0]);
                        acc[oc][1] = fmaf(colv[2 + kw], wv, acc[oc][1]);
                        acc[oc][2] = fmaf(colv[4 + kw], wv, acc[oc][2]);
                        acc[oc][3] = fmaf(colv[6 + kw], wv, acc[oc][3]);
                    }
                }
            }
        }
        #pragma unroll
        for (int oc = 0; oc < 4; oc++) {
            float* o = arena + oc * 1155 + (oh + 1) * 35 + ow0 + 1;
            #pragma unroll
            for (int j = 0; j < 4; j++) o[j] = fmaxf(acc[oc][j], 0.f);
        }
    }
    __syncthreads();

    // ---- conv2 -> registers ----
    float r2[2][4];
    {
        const int oc0 = __builtin_amdgcn_readfirstlane(tid >> 6);
        const int oh  = lane >> 2, ow0 = (lane & 3) * 4;
        {
            const float ba = b2[oc0], bb = b2[oc0 + 4];
            #pragma unroll
            for (int j = 0; j < 4; j++) { r2[0][j] = ba; r2[1][j] = bb; }
        }
        const int c0s = ow0 * 2;
        #pragma unroll
        for (int ic = 0; ic < 4; ic++) {
            const float* base = arena + ic * 1155;
            #pragma unroll
            for (int kh = 0; kh < 3; kh++) {
                const int ihs = oh * 2 + kh;
                float colv[9];
                #pragma unroll
                for (int cc = 0; cc < 9; cc++) colv[cc] = base[ihs * 35 + c0s + cc];
                #pragma unroll
                for (int kw = 0; kw < 3; kw++) {
                    const float wa = w2[((oc0    ) * 4 + ic) * 9 + kh * 3 + kw];
                    const float wb = w2[((oc0 + 4) * 4 + ic) * 9 + kh * 3 + kw];
                    #pragma unroll
                    for (int j = 0; j < 4; j++) {
                        r2[0][j] = fmaf(colv[2 * j + kw], wa, r2[0][j]);
                        r2[1][j] = fmaf(colv[2 * j + kw], wb, r2[1][j]);
                    }
                }
            }
        }
    }
    __syncthreads();

    // ---- conv2-out halo overlay ----
    for (int i = tid; i < 576; i += 256) {
        const int ch = i / 72, j = i - ch * 72;
        if (j < 18)      arena[ch * 324 + j] = 0.f;
        else if (j < 36) arena[ch * 324 + 17 * 18 + (j - 18)] = 0.f;
        else if (j < 52) arena[ch * 324 + (j - 35) * 18] = 0.f;
        else if (j < 68) arena[ch * 324 + (j - 51) * 18 + 17] = 0.f;
    }
    {
        const int oc0 = __builtin_amdgcn_readfirstlane(tid >> 6);
        const int oh  = lane >> 2, ow0 = (lane & 3) * 4;
        float* oA = arena + oc0 * 324       + (oh + 1) * 18 + ow0 + 1;
        float* oB = arena + (oc0 + 4) * 324 + (oh + 1) * 18 + ow0 + 1;
        #pragma unroll
        for (int j = 0; j < 4; j++) { oA[j] = fmaxf(r2[0][j], 0.f); oB[j] = fmaxf(r2[1][j], 0.f); }
    }
    __syncthreads();

    // ---- conv3 + fused 8x8 avg pool ----
    {
        const int oc = tid >> 4, s = tid & 15;
        const int tr = (s >> 2) * 4, tc = (s & 3) * 4;
        float acc[16];
        const float bv = w3s[1152 + oc];
        #pragma unroll
        for (int k = 0; k < 16; k++) acc[k] = bv;
        #pragma unroll
        for (int ic = 0; ic < 8; ic++) {
            const float* xc = arena + ic * 324;
            float p[6][6];
            #pragma unroll
            for (int dr = 0; dr < 6; dr++)
                #pragma unroll
                for (int dc = 0; dc < 6; dc++)
                    p[dr][dc] = xc[(tr + dr) * 18 + (tc + dc)];
            float wv[9];
            #pragma unroll
            for (int k = 0; k < 9; k++) wv[k] = w3s[oc * 72 + ic * 9 + k];
            #pragma unroll
            for (int r = 0; r < 4; r++)
                #pragma unroll
                for (int c = 0; c < 4; c++) {
                    float a = acc[r * 4 + c];
                    #pragma unroll
                    for (int kh = 0; kh < 3; kh++)
                        #pragma unroll
                        for (int kw = 0; kw < 3; kw++)
                            a = fmaf(p[r + kh][c + kw], wv[kh * 3 + kw], a);
                    acc[r * 4 + c] = a;
                }
        }
        float ps = 0.f;
        #pragma unroll
        for (int k = 0; k < 16; k++) ps += fmaxf(acc[k], 0.f);
        ps += __shfl_xor(ps, 1, 64);
        ps += __shfl_xor(ps, 4, 64);
        if ((s & 5) == 0) {
            const int ii = s >> 3, jj = (s >> 1) & 1;
            poolout[b * 64 + oc * 4 + ii * 2 + jj] = ps * (1.f / 64.f);
        }
    }
}

// ================= Kernel B: head, 2 elements per block, 2048 blocks (8 blocks/CU) =================
__global__ __launch_bounds__(256)
void head_kernel(const float* __restrict__ poolin,
                 const float* __restrict__ wf, const float* __restrict__ bf,
                 const float* __restrict__ qw,
                 const float* __restrict__ wc1, const float* __restrict__ bc1,
                 const float* __restrict__ wc2, const float* __restrict__ bc2,
                 const float* __restrict__ wc3, const float* __restrict__ bc3,
                 const float* __restrict__ wc4, const float* __restrict__ bc4,
                 const float* __restrict__ wc5, const float* __restrict__ bc5,
                 float* __restrict__ out)
{
    __shared__ __align__(16) float pool_s[128];    // [2][64]
    __shared__ __align__(16) float feats[512];     // [2][256]
    __shared__ __align__(16) float h1[400];        // [2][200]
    __shared__ __align__(16) float h2[304];        // [2][152] (152 keeps 16B align)
    __shared__ __align__(16) float h3[200];        // [2][100]
    __shared__ __align__(16) float h4[104];        // [2][52]
    __shared__ float zbuf[2];
    __shared__ float csc[56], css[56];

    const int tid  = threadIdx.x;
    const int blk  = blockIdx.x;
    const int lane = tid & 63;
    const int wv   = tid >> 6;

    if (tid < 128) pool_s[tid] = poolin[(size_t)blk * 128 + tid];
    if (tid < 56) {
        float th = qw[tid] * 0.5f;
        csc[tid] = cosf(th);
        css[tid] = sinf(th);
    }
    __syncthreads();

    // ---- fc: thread t owns feature t for both elements ----
    {
        float acc0 = bf[tid], acc1 = acc0;
        const float4* wr = (const float4*)(wf + tid * 64);
        const float4* p0 = (const float4*)pool_s;
        const float4* p1 = (const float4*)(pool_s + 64);
        #pragma unroll
        for (int k = 0; k < 16; k++) {
            float4 w = wr[k];
            float4 a = p0[k], bq = p1[k];
            acc0 = fmaf(w.x, a.x, acc0); acc0 = fmaf(w.y, a.y, acc0);
            acc0 = fmaf(w.z, a.z, acc0); acc0 = fmaf(w.w, a.w, acc0);
            acc1 = fmaf(w.x, bq.x, acc1); acc1 = fmaf(w.y, bq.y, acc1);
            acc1 = fmaf(w.z, bq.z, acc1); acc1 = fmaf(w.w, bq.w, acc1);
        }
        feats[tid]       = fmaxf(acc0, 0.f);
        feats[256 + tid] = fmaxf(acc1, 0.f);
    }
    __syncthreads();

    // ---- quantum: waves 0,1 handle elements 0,1 ----
    if (wv < 2) {
        const float* base = feats + wv * 256;
        float v0 = base[lane], v1 = base[64 + lane];
        float v2 = base[128 + lane], v3 = base[192 + lane];
        float ssq = v0 * v0 + v1 * v1 + v2 * v2 + v3 * v3;
        #pragma unroll
        for (int off = 1; off < 64; off <<= 1) ssq += __shfl_xor(ssq, off, 64);
        const float inv = 1.0f / fmaxf(sqrtf(ssq), 1e-12f);
        v0 *= inv; v1 *= inv; v2 *= inv; v3 *= inv;

        for (int l = 0; l < 7; l++) {
            {
                float c = csc[l * 8 + 0], s = css[l * 8 + 0];
                float n0 = c * v0 - s * v2, n2 = s * v0 + c * v2;
                float n1 = c * v1 - s * v3, n3 = s * v1 + c * v3;
                float c1 = csc[l * 8 + 1], s1 = css[l * 8 + 1];
                v0 = c1 * n0 - s1 * n1; v1 = s1 * n0 + c1 * n1;
                v2 = c1 * n2 - s1 * n3; v3 = s1 * n2 + c1 * n3;
            }
            #pragma unroll
            for (int q = 2; q < 8; q++) {
                const int m = 1 << (7 - q);
                const float c = csc[l * 8 + q], s = css[l * 8 + q];
                const float sgn = (lane & m) ? s : -s;
                float t0 = __shfl_xor(v0, m, 64);
                float t1 = __shfl_xor(v1, m, 64);
                float t2 = __shfl_xor(v2, m, 64);
                float t3 = __shfl_xor(v3, m, 64);
                v0 = fmaf(sgn, t0, c * v0);
                v1 = fmaf(sgn, t1, c * v1);
                v2 = fmaf(sgn, t2, c * v2);
                v3 = fmaf(sgn, t3, c * v3);
            }
            { float t = v2; v2 = v3; v3 = t; }
            v1 = __shfl_xor(v1, 32, 64);
            v3 = __shfl_xor(v3, 32, 64);
            #pragma unroll
            for (int q = 2; q < 7; q++) {
                const int mc = 1 << (7 - q), mt = 1 << (6 - q);
                float t0 = __shfl_xor(v0, mt, 64);
                float t1 = __shfl_xor(v1, mt, 64);
                float t2 = __shfl_xor(v2, mt, 64);
                float t3 = __shfl_xor(v3, mt, 64);
                if (lane & mc) { v0 = t0; v1 = t1; v2 = t2; v3 = t3; }
            }
        }
        float m0 = v0 * v0 + v1 * v1 - v2 * v2 - v3 * v3;
        #pragma unroll
        for (int off = 1; off < 64; off <<= 1) m0 += __shfl_xor(m0, off, 64);
        if (lane == 0) zbuf[wv] = m0;
    }
    __syncthreads();

    // ---- classifier MLP, weights in registers reused across 2 elements ----
    if (tid < 200) {
        const float w = wc1[tid], bv = bc1[tid];
        h1[tid]       = fmaxf(fmaf(zbuf[0], w, bv), 0.f);
        h1[200 + tid] = fmaxf(fmaf(zbuf[1], w, bv), 0.f);
    }
    __syncthreads();
    if (tid < 150) {
        float acc0 = bc2[tid], acc1 = acc0;
        const float4* wr = (const float4*)(wc2 + tid * 200);
        const float4* hA = (const float4*)h1;
        const float4* hB = (const float4*)(h1 + 200);
        #pragma unroll 10
        for (int k = 0; k < 50; k++) {
            float4 w = wr[k];
            float4 a = hA[k], bq = hB[k];
            acc0 = fmaf(w.x, a.x, acc0); acc0 = fmaf(w.y, a.y, acc0);
            acc0 = fmaf(w.z, a.z, acc0); acc0 = fmaf(w.w, a.w, acc0);
            acc1 = fmaf(w.x, bq.x, acc1); acc1 = fmaf(w.y, bq.y, acc1);
            acc1 = fmaf(w.z, bq.z, acc1); acc1 = fmaf(w.w, bq.w, acc1);
        }
        h2[tid]       = fmaxf(acc0, 0.f);
        h2[152 + tid] = fmaxf(acc1, 0.f);
    }
    __syncthreads();
    if (tid < 100) {
        float acc0 = bc3[tid], acc1 = acc0;
        const float2* wr = (const float2*)(wc3 + tid * 150);
        const float2* hA = (const float2*)h2;
        const float2* hB = (const float2*)(h2 + 152);
        #pragma unroll 15
        for (int k = 0; k < 75; k++) {
            float2 w = wr[k];
            float2 a = hA[k], bq = hB[k];
            acc0 = fmaf(w.x, a.x, fmaf(w.y, a.y, acc0));
            acc1 = fmaf(w.x, bq.x, fmaf(w.y, bq.y, acc1));
        }
        h3[tid]       = fmaxf(acc0, 0.f);
        h3[100 + tid] = fmaxf(acc1, 0.f);
    }
    __syncthreads();
    if (tid < 50) {
        float acc0 = bc4[tid], acc1 = acc0;
        const float4* wr = (const float4*)(wc4 + tid * 100);
        const float4* hA = (const float4*)h3;
        const float4* hB = (const float4*)(h3 + 100);
        #pragma unroll
        for (int k = 0; k < 25; k++) {
            float4 w = wr[k];
            float4 a = hA[k], bq = hB[k];
            acc0 = fmaf(w.x, a.x, acc0); acc0 = fmaf(w.y, a.y, acc0);
            acc0 = fmaf(w.z, a.z, acc0); acc0 = fmaf(w.w, a.w, acc0);
            acc1 = fmaf(w.x, bq.x, acc1); acc1 = fmaf(w.y, bq.y, acc1);
            acc1 = fmaf(w.z, bq.z, acc1); acc1 = fmaf(w.w, bq.w, acc1);
        }
        h4[tid]      = fmaxf(acc0, 0.f);
        h4[52 + tid] = fmaxf(acc1, 0.f);
    }
    __syncthreads();
    if (tid < 2) {
        float acc = bc5[0];
        const float2* wr = (const float2*)wc5;
        const float2* hp = (const float2*)(h4 + tid * 52);
        #pragma unroll
        for (int k = 0; k < 25; k++) {
            float2 w = wr[k], hv = hp[k];
            acc = fmaf(w.x, hv.x, fmaf(w.y, hv.y, acc));
        }
        out[blk * 2 + tid] = 1.0f / (1.0f + expf(-acc));
    }
}

extern "C" void kernel_launch(void* const* d_in, const int* in_sizes, int n_in,
                              void* d_out, int out_size, void* d_ws, size_t ws_size,
                              hipStream_t stream) {
    const float* x   = (const float*)d_in[0];
    const float* w1  = (const float*)d_in[1];
    const float* b1  = (const float*)d_in[2];
    const float* w2  = (const float*)d_in[3];
    const float* b2  = (const float*)d_in[4];
    const float* w3  = (const float*)d_in[5];
    const float* b3  = (const float*)d_in[6];
    const float* wf  = (const float*)d_in[7];
    const float* bf  = (const float*)d_in[8];
    const float* qw  = (const float*)d_in[9];
    const float* wc1 = (const float*)d_in[10];
    const float* bc1 = (const float*)d_in[11];
    const float* wc2 = (const float*)d_in[12];
    const float* bc2 = (const float*)d_in[13];
    const float* wc3 = (const float*)d_in[14];
    const float* bc3 = (const float*)d_in[15];
    const float* wc4 = (const float*)d_in[16];
    const float* bc4 = (const float*)d_in[17];
    const float* wc5 = (const float*)d_in[18];
    const float* bc5 = (const float*)d_in[19];
    float* out = (float*)d_out;

    float* poolbuf = (float*)d_ws;   // 4096*64 floats = 1 MB

    convpool_kernel<<<4096, 256, 0, stream>>>(x, w1, b1, w2, b2, w3, b3, poolbuf);
    head_kernel<<<2048, 256, 0, stream>>>(poolbuf, wf, bf, qw,
                                          wc1, bc1, wc2, bc2, wc3, bc3,
                                          wc4, bc4, wc5, bc5, out);
}

// Round 7
// 217.333 us; speedup vs baseline: 1.2121x; 1.0457x over previous
//
#include <hip/hip_runtime.h>
#include <math.h>

typedef float v2f __attribute__((ext_vector_type(2)));
#define FMA2(a, b, c) __builtin_elementwise_fma((a), (b), (c))

// ================= Kernel A: conv1+conv2+conv3+pool fused, one block per image =================
// Packed-FMA (v_pk_fma_f32) variant: 2-wide vector accumulators, per-output order unchanged.
__global__ __launch_bounds__(256, 6)
void convpool_kernel(const float* __restrict__ x,
                     const float* __restrict__ w1, const float* __restrict__ b1,
                     const float* __restrict__ w2, const float* __restrict__ b2,
                     const float* __restrict__ w3, const float* __restrict__ b3,
                     float* __restrict__ poolout)
{
    __shared__ __align__(16) float arena[4620];
    __shared__ __align__(16) float w3s[1168];
    const int tid  = threadIdx.x;
    const int b    = blockIdx.x;
    const int lane = tid & 63;

    for (int i = tid; i < 1168; i += 256) w3s[i] = (i < 1152) ? w3[i] : b3[i - 1152];
    for (int i = tid; i < 140; i += 256) { int oc = i / 35, c = i - oc * 35; arena[oc * 1155 + c] = 0.f; }
    for (int i = tid; i < 132; i += 256) { int oc = i / 33, r = i - oc * 33; arena[oc * 1155 + r * 35] = 0.f; }

    // ---- conv1: k5 s2 p2, 4 oc x (2+2) px per thread, packed ----
    {
        const float* xb = x + (size_t)b * 4096;
        const int oh  = tid >> 3;
        const int ow  = tid & 7;
        const int ow0 = ow * 4;
        const int c0  = ow0 * 2 - 2;
        const bool cmL = (ow == 0);
        const bool cmR = (ow == 7);
        v2f a01[4], a23[4];
        #pragma unroll
        for (int oc = 0; oc < 4; oc++) {
            const float bv = b1[oc];
            a01[oc] = (v2f){bv, bv};
            a23[oc] = (v2f){bv, bv};
        }
        #pragma unroll
        for (int kh = 0; kh < 5; kh++) {
            const int ih = oh * 2 - 2 + kh;
            if (ih >= 0 && ih < 64) {
                const float* row = xb + ih * 64;
                float colv[11];
                {
                    float v0 = row[cmL ? 0 : c0];
                    float v1 = row[cmL ? 0 : c0 + 1];
                    float vA = row[cmR ? 63 : c0 + 10];
                    colv[0]  = cmL ? 0.f : v0;
                    colv[1]  = cmL ? 0.f : v1;
                    colv[10] = cmR ? 0.f : vA;
                }
                #pragma unroll
                for (int cc = 2; cc < 10; cc++) colv[cc] = row[c0 + cc];
                #pragma unroll
                for (int kw = 0; kw < 5; kw++) {
                    const v2f c01 = {colv[kw],     colv[kw + 2]};
                    const v2f c23 = {colv[kw + 4], colv[kw + 6]};
                    #pragma unroll
                    for (int oc = 0; oc < 4; oc++) {
                        const float wv = w1[oc * 25 + kh * 5 + kw];
                        const v2f ws = {wv, wv};
                        a01[oc] = FMA2(c01, ws, a01[oc]);
                        a23[oc] = FMA2(c23, ws, a23[oc]);
                    }
                }
            }
        }
        #pragma unroll
        for (int oc = 0; oc < 4; oc++) {
            float* o = arena + oc * 1155 + (oh + 1) * 35 + ow0 + 1;
            o[0] = fmaxf(a01[oc].x, 0.f); o[1] = fmaxf(a01[oc].y, 0.f);
            o[2] = fmaxf(a23[oc].x, 0.f); o[3] = fmaxf(a23[oc].y, 0.f);
        }
    }
    __syncthreads();

    // ---- conv2: k3 s2 p1, 2 oc x (2+2) px per thread -> registers, packed ----
    v2f rA01, rA23, rB01, rB23;
    {
        const int oc0 = __builtin_amdgcn_readfirstlane(tid >> 6);
        const int oh  = lane >> 2, ow0 = (lane & 3) * 4;
        {
            const float ba = b2[oc0], bb = b2[oc0 + 4];
            rA01 = (v2f){ba, ba}; rA23 = (v2f){ba, ba};
            rB01 = (v2f){bb, bb}; rB23 = (v2f){bb, bb};
        }
        const int c0s = ow0 * 2;
        #pragma unroll
        for (int ic = 0; ic < 4; ic++) {
            const float* base = arena + ic * 1155;
            #pragma unroll
            for (int kh = 0; kh < 3; kh++) {
                const int ihs = oh * 2 + kh;
                float colv[9];
                #pragma unroll
                for (int cc = 0; cc < 9; cc++) colv[cc] = base[ihs * 35 + c0s + cc];
                #pragma unroll
                for (int kw = 0; kw < 3; kw++) {
                    const v2f c01 = {colv[kw],     colv[kw + 2]};
                    const v2f c23 = {colv[kw + 4], colv[kw + 6]};
                    const float wa = w2[((oc0    ) * 4 + ic) * 9 + kh * 3 + kw];
                    const float wb = w2[((oc0 + 4) * 4 + ic) * 9 + kh * 3 + kw];
                    const v2f was = {wa, wa}, wbs = {wb, wb};
                    rA01 = FMA2(c01, was, rA01);
                    rA23 = FMA2(c23, was, rA23);
                    rB01 = FMA2(c01, wbs, rB01);
                    rB23 = FMA2(c23, wbs, rB23);
                }
            }
        }
    }
    __syncthreads();

    // ---- conv2-out halo overlay ----
    for (int i = tid; i < 576; i += 256) {
        const int ch = i / 72, j = i - ch * 72;
        if (j < 18)      arena[ch * 324 + j] = 0.f;
        else if (j < 36) arena[ch * 324 + 17 * 18 + (j - 18)] = 0.f;
        else if (j < 52) arena[ch * 324 + (j - 35) * 18] = 0.f;
        else if (j < 68) arena[ch * 324 + (j - 51) * 18 + 17] = 0.f;
    }
    {
        const int oc0 = __builtin_amdgcn_readfirstlane(tid >> 6);
        const int oh  = lane >> 2, ow0 = (lane & 3) * 4;
        float* oA = arena + oc0 * 324       + (oh + 1) * 18 + ow0 + 1;
        float* oB = arena + (oc0 + 4) * 324 + (oh + 1) * 18 + ow0 + 1;
        oA[0] = fmaxf(rA01.x, 0.f); oA[1] = fmaxf(rA01.y, 0.f);
        oA[2] = fmaxf(rA23.x, 0.f); oA[3] = fmaxf(rA23.y, 0.f);
        oB[0] = fmaxf(rB01.x, 0.f); oB[1] = fmaxf(rB01.y, 0.f);
        oB[2] = fmaxf(rB23.x, 0.f); oB[3] = fmaxf(rB23.y, 0.f);
    }
    __syncthreads();

    // ---- conv3 + fused 8x8 avg pool: thread = (oc, 4x4 tile), packed over col-pairs ----
    {
        const int oc = tid >> 4, s = tid & 15;
        const int tr = (s >> 2) * 4, tc = (s & 3) * 4;
        v2f acc2[4][2];   // [r][c-pair]: (c0,c1) and (c2,c3)
        const float bv = w3s[1152 + oc];
        #pragma unroll
        for (int r = 0; r < 4; r++) {
            acc2[r][0] = (v2f){bv, bv};
            acc2[r][1] = (v2f){bv, bv};
        }
        #pragma unroll
        for (int ic = 0; ic < 8; ic++) {
            const float* xc = arena + ic * 324;
            float p[6][6];
            #pragma unroll
            for (int dr = 0; dr < 6; dr++)
                #pragma unroll
                for (int dc = 0; dc < 6; dc++)
                    p[dr][dc] = xc[(tr + dr) * 18 + (tc + dc)];
            float wv[9];
            #pragma unroll
            for (int k = 0; k < 9; k++) wv[k] = w3s[oc * 72 + ic * 9 + k];
            #pragma unroll
            for (int r = 0; r < 4; r++) {
                #pragma unroll
                for (int c2 = 0; c2 < 2; c2++) {
                    const int cb = c2 * 2;
                    v2f a = acc2[r][c2];
                    #pragma unroll
                    for (int kh = 0; kh < 3; kh++) {
                        const int rr = r + kh;
                        #pragma unroll
                        for (int kw = 0; kw < 3; kw++) {
                            const v2f pp = {p[rr][cb + kw], p[rr][cb + kw + 1]};
                            const float w = wv[kh * 3 + kw];
                            const v2f ws = {w, w};
                            a = FMA2(pp, ws, a);
                        }
                    }
                    acc2[r][c2] = a;
                }
            }
        }
        // relu + tile sum in original (r, c ascending) order
        float ps = 0.f;
        #pragma unroll
        for (int r = 0; r < 4; r++) {
            ps += fmaxf(acc2[r][0].x, 0.f);
            ps += fmaxf(acc2[r][0].y, 0.f);
            ps += fmaxf(acc2[r][1].x, 0.f);
            ps += fmaxf(acc2[r][1].y, 0.f);
        }
        ps += __shfl_xor(ps, 1, 64);
        ps += __shfl_xor(ps, 4, 64);
        if ((s & 5) == 0) {
            const int ii = s >> 3, jj = (s >> 1) & 1;
            poolout[b * 64 + oc * 4 + ii * 2 + jj] = ps * (1.f / 64.f);
        }
    }
}

// ================= Kernel B: head, 4 elements per block, 1024 blocks (R4 config) =================
__global__ __launch_bounds__(256)
void head_kernel(const float* __restrict__ poolin,
                 const float* __restrict__ wf, const float* __restrict__ bf,
                 const float* __restrict__ qw,
                 const float* __restrict__ wc1, const float* __restrict__ bc1,
                 const float* __restrict__ wc2, const float* __restrict__ bc2,
                 const float* __restrict__ wc3, const float* __restrict__ bc3,
                 const float* __restrict__ wc4, const float* __restrict__ bc4,
                 const float* __restrict__ wc5, const float* __restrict__ bc5,
                 float* __restrict__ out)
{
    __shared__ __align__(16) float pool_s[256];    // [4][64]
    __shared__ __align__(16) float feats[1024];    // [4][256]
    __shared__ __align__(16) float h1[800];        // [4][200]
    __shared__ __align__(16) float h2[600];        // [4][150]
    __shared__ __align__(16) float h3[400];        // [4][100]
    __shared__ __align__(16) float h4[200];        // [4][50]
    __shared__ float zbuf[4];
    __shared__ float csc[56], css[56];

    const int tid  = threadIdx.x;
    const int blk  = blockIdx.x;
    const int lane = tid & 63;
    const int wv   = tid >> 6;

    pool_s[tid] = poolin[(size_t)blk * 256 + tid];
    if (tid < 56) {
        float th = qw[tid] * 0.5f;
        csc[tid] = cosf(th);
        css[tid] = sinf(th);
    }
    __syncthreads();

    // ---- fc: thread t owns feature t for all 4 elements ----
    {
        float acc[4];
        const float bv = bf[tid];
        #pragma unroll
        for (int e = 0; e < 4; e++) acc[e] = bv;
        const float4* wr = (const float4*)(wf + tid * 64);
        #pragma unroll
        for (int kc = 0; kc < 4; kc++) {
            float4 w0 = wr[kc * 4 + 0], w1_ = wr[kc * 4 + 1], w2_ = wr[kc * 4 + 2], w3_ = wr[kc * 4 + 3];
            #pragma unroll
            for (int e = 0; e < 4; e++) {
                const float4* pp = (const float4*)(pool_s + e * 64 + kc * 16);
                float4 p0 = pp[0], p1 = pp[1], p2 = pp[2], p3 = pp[3];
                float a = acc[e];
                a = fmaf(w0.x, p0.x, a); a = fmaf(w0.y, p0.y, a); a = fmaf(w0.z, p0.z, a); a = fmaf(w0.w, p0.w, a);
                a = fmaf(w1_.x, p1.x, a); a = fmaf(w1_.y, p1.y, a); a = fmaf(w1_.z, p1.z, a); a = fmaf(w1_.w, p1.w, a);
                a = fmaf(w2_.x, p2.x, a); a = fmaf(w2_.y, p2.y, a); a = fmaf(w2_.z, p2.z, a); a = fmaf(w2_.w, p2.w, a);
                a = fmaf(w3_.x, p3.x, a); a = fmaf(w3_.y, p3.y, a); a = fmaf(w3_.z, p3.z, a); a = fmaf(w3_.w, p3.w, a);
                acc[e] = a;
            }
        }
        #pragma unroll
        for (int e = 0; e < 4; e++) feats[e * 256 + tid] = fmaxf(acc[e], 0.f);
    }
    __syncthreads();

    // ---- quantum: wave wv handles element wv; amp idx = j*64 + lane ----
    {
        const float* base = feats + wv * 256;
        float v0 = base[lane], v1 = base[64 + lane];
        float v2 = base[128 + lane], v3 = base[192 + lane];
        float ssq = v0 * v0 + v1 * v1 + v2 * v2 + v3 * v3;
        #pragma unroll
        for (int off = 1; off < 64; off <<= 1) ssq += __shfl_xor(ssq, off, 64);
        const float inv = 1.0f / fmaxf(sqrtf(ssq), 1e-12f);
        v0 *= inv; v1 *= inv; v2 *= inv; v3 *= inv;

        for (int l = 0; l < 7; l++) {
            {
                float c = csc[l * 8 + 0], s = css[l * 8 + 0];
                float n0 = c * v0 - s * v2, n2 = s * v0 + c * v2;
                float n1 = c * v1 - s * v3, n3 = s * v1 + c * v3;
                float c1 = csc[l * 8 + 1], s1 = css[l * 8 + 1];
                v0 = c1 * n0 - s1 * n1; v1 = s1 * n0 + c1 * n1;
                v2 = c1 * n2 - s1 * n3; v3 = s1 * n2 + c1 * n3;
            }
            #pragma unroll
            for (int q = 2; q < 8; q++) {
                const int m = 1 << (7 - q);
                const float c = csc[l * 8 + q], s = css[l * 8 + q];
                const float sgn = (lane & m) ? s : -s;
                float t0 = __shfl_xor(v0, m, 64);
                float t1 = __shfl_xor(v1, m, 64);
                float t2 = __shfl_xor(v2, m, 64);
                float t3 = __shfl_xor(v3, m, 64);
                v0 = fmaf(sgn, t0, c * v0);
                v1 = fmaf(sgn, t1, c * v1);
                v2 = fmaf(sgn, t2, c * v2);
                v3 = fmaf(sgn, t3, c * v3);
            }
            { float t = v2; v2 = v3; v3 = t; }
            v1 = __shfl_xor(v1, 32, 64);
            v3 = __shfl_xor(v3, 32, 64);
            #pragma unroll
            for (int q = 2; q < 7; q++) {
                const int mc = 1 << (7 - q), mt = 1 << (6 - q);
                float t0 = __shfl_xor(v0, mt, 64);
                float t1 = __shfl_xor(v1, mt, 64);
                float t2 = __shfl_xor(v2, mt, 64);
                float t3 = __shfl_xor(v3, mt, 64);
                if (lane & mc) { v0 = t0; v1 = t1; v2 = t2; v3 = t3; }
            }
        }
        float m0 = v0 * v0 + v1 * v1 - v2 * v2 - v3 * v3;
        #pragma unroll
        for (int off = 1; off < 64; off <<= 1) m0 += __shfl_xor(m0, off, 64);
        if (lane == 0) zbuf[wv] = m0;
    }
    __syncthreads();

    // ---- classifier MLP, weights in registers reused across 4 elements ----
    if (tid < 200) {
        const float w = wc1[tid], bv = bc1[tid];
        #pragma unroll
        for (int e = 0; e < 4; e++) h1[e * 200 + tid] = fmaxf(fmaf(zbuf[e], w, bv), 0.f);
    }
    __syncthreads();
    if (tid < 150) {
        float acc[4];
        const float bv = bc2[tid];
        #pragma unroll
        for (int e = 0; e < 4; e++) acc[e] = bv;
        const float4* wr = (const float4*)(wc2 + tid * 200);
        for (int kc = 0; kc < 25; kc++) {
            float4 wa = wr[2 * kc], wb = wr[2 * kc + 1];
            #pragma unroll
            for (int e = 0; e < 4; e++) {
                const float4* hp = (const float4*)(h1 + e * 200) + 2 * kc;
                float4 ha = hp[0], hb = hp[1];
                float a = acc[e];
                a = fmaf(wa.x, ha.x, a); a = fmaf(wa.y, ha.y, a); a = fmaf(wa.z, ha.z, a); a = fmaf(wa.w, ha.w, a);
                a = fmaf(wb.x, hb.x, a); a = fmaf(wb.y, hb.y, a); a = fmaf(wb.z, hb.z, a); a = fmaf(wb.w, hb.w, a);
                acc[e] = a;
            }
        }
        #pragma unroll
        for (int e = 0; e < 4; e++) h2[e * 150 + tid] = fmaxf(acc[e], 0.f);
    }
    __syncthreads();
    if (tid < 100) {
        float acc[4];
        const float bv = bc3[tid];
        #pragma unroll
        for (int e = 0; e < 4; e++) acc[e] = bv;
        const float2* wr = (const float2*)(wc3 + tid * 150);
        for (int k = 0; k < 75; k++) {
            float2 wa = wr[k];
            #pragma unroll
            for (int e = 0; e < 4; e++) {
                float2 hv = ((const float2*)(h2 + e * 150))[k];
                acc[e] = fmaf(wa.x, hv.x, fmaf(wa.y, hv.y, acc[e]));
            }
        }
        #pragma unroll
        for (int e = 0; e < 4; e++) h3[e * 100 + tid] = fmaxf(acc[e], 0.f);
    }
    __syncthreads();
    if (tid < 50) {
        float acc[4];
        const float bv = bc4[tid];
        #pragma unroll
        for (int e = 0; e < 4; e++) acc[e] = bv;
        const float4* wr = (const float4*)(wc4 + tid * 100);
        for (int kc = 0; kc < 25; kc++) {
            float4 wa = wr[kc];
            #pragma unroll
            for (int e = 0; e < 4; e++) {
                float4 hv = ((const float4*)(h3 + e * 100))[kc];
                float a = acc[e];
                a = fmaf(wa.x, hv.x, a); a = fmaf(wa.y, hv.y, a);
                a = fmaf(wa.z, hv.z, a); a = fmaf(wa.w, hv.w, a);
                acc[e] = a;
            }
        }
        #pragma unroll
        for (int e = 0; e < 4; e++) h4[e * 50 + tid] = fmaxf(acc[e], 0.f);
    }
    __syncthreads();
    if (tid < 4) {
        float acc = bc5[0];
        const float2* wr = (const float2*)wc5;
        #pragma unroll
        for (int k = 0; k < 25; k++) {
            float2 wa = wr[k];
            float2 hv = ((const float2*)(h4 + tid * 50))[k];
            acc = fmaf(wa.x, hv.x, fmaf(wa.y, hv.y, acc));
        }
        out[blk * 4 + tid] = 1.0f / (1.0f + expf(-acc));
    }
}

extern "C" void kernel_launch(void* const* d_in, const int* in_sizes, int n_in,
                              void* d_out, int out_size, void* d_ws, size_t ws_size,
                              hipStream_t stream) {
    const float* x   = (const float*)d_in[0];
    const float* w1  = (const float*)d_in[1];
    const float* b1  = (const float*)d_in[2];
    const float* w2  = (const float*)d_in[3];
    const float* b2  = (const float*)d_in[4];
    const float* w3  = (const float*)d_in[5];
    const float* b3  = (const float*)d_in[6];
    const float* wf  = (const float*)d_in[7];
    const float* bf  = (const float*)d_in[8];
    const float* qw  = (const float*)d_in[9];
    const float* wc1 = (const float*)d_in[10];
    const float* bc1 = (const float*)d_in[11];
    const float* wc2 = (const float*)d_in[12];
    const float* bc2 = (const float*)d_in[13];
    const float* wc3 = (const float*)d_in[14];
    const float* bc3 = (const float*)d_in[15];
    const float* wc4 = (const float*)d_in[16];
    const float* bc4 = (const float*)d_in[17];
    const float* wc5 = (const float*)d_in[18];
    const float* bc5 = (const float*)d_in[19];
    float* out = (float*)d_out;

    float* poolbuf = (float*)d_ws;   // 4096*64 floats = 1 MB

    convpool_kernel<<<4096, 256, 0, stream>>>(x, w1, b1, w2, b2, w3, b3, poolbuf);
    head_kernel<<<1024, 256, 0, stream>>>(poolbuf, wf, bf, qw,
                                          wc1, bc1, wc2, bc2, wc3, bc3,
                                          wc4, bc4, wc5, bc5, out);
}